// Round 3
// baseline (421.443 us; speedup 1.0000x reference)
//
#include <hip/hip_runtime.h>
#include <hip/hip_bf16.h>
#include <hip/hip_fp16.h>
#include <float.h>

#define D 128
#define NGRAPHS 64
#define BKSHIFT 9
#define BKNODES 512     // nodes per bucket
#define MAXBK 256       // max buckets (N<=131072)
#define PCH 2048        // edges per partition block (256 thr x 8)
#define HCH 4096        // histogram chunk

typedef _Float16 h8 __attribute__((ext_vector_type(8)));
typedef float f4 __attribute__((ext_vector_type(4)));

// ---- ordered-float encoding for atomicMax on unsigned ----
__device__ __forceinline__ unsigned fkey(float f){
  unsigned u = __float_as_uint(f);
  return (u & 0x80000000u) ? ~u : (u | 0x80000000u);
}
__device__ __forceinline__ float funkey(unsigned k){
  unsigned u = (k & 0x80000000u) ? (k ^ 0x80000000u) : ~k;
  return __uint_as_float(u);
}

// ---- W fp32 row-major -> fp16 MFMA B-frag swizzle for one "pair" unit ----
__device__ __forceinline__ void wcvt_pair(const float* __restrict__ W,
    _Float16* __restrict__ dstp, int pair, int lane){
  int quad = lane >> 4;
  int n    = lane & 15;
  int k0 = pair >> 3;
  int tt = pair & 7;
  _Float16 v[8];
  #pragma unroll
  for (int j = 0; j < 8; j++){
    int k = k0 * 32 + quad * 8 + j;
    v[j] = (_Float16)W[k * 128 + 16 * tt + n];
  }
  *(uint4*)&dstp[((size_t)pair * 64 + lane) * 8] = *(uint4*)v;
}

// 0) W0 swizzle (blocks 0..7) + dst-bucket histogram (blocks 8..)
//    bcnt/bCur/pk zeroed by hipMemsetAsync before this kernel.
__global__ __launch_bounds__(256) void k_wcvt0h(const float* __restrict__ W0,
    _Float16* __restrict__ Wsw, const int* __restrict__ dst,
    int* __restrict__ bcnt, int E){
  __shared__ int h[MAXBK];
  if (blockIdx.x < 8){
    int lane = threadIdx.x & 63;
    int pair = blockIdx.x * 4 + (threadIdx.x >> 6);
    wcvt_pair(W0, Wsw, pair, lane);
    return;
  }
  int t = threadIdx.x;
  for (int i = t; i < MAXBK; i += 256) h[i] = 0;
  __syncthreads();
  int e0 = (blockIdx.x - 8) * HCH;
  #pragma unroll
  for (int j = 0; j < HCH / 256; j++){
    int e = e0 + t + j * 256;
    if (e < E) atomicAdd(&h[dst[e] >> BKSHIFT], 1);
  }
  __syncthreads();
  for (int i = t; i < MAXBK; i += 256) if (h[i]) atomicAdd(&bcnt[i], h[i]);
}

// 1) MEGA2: [0,gb): gemm0 fp32-A MFMA (x@W0 -> tmp, row-major);
//    [gb,gb+npart): edge partition into epart (hidden under gemm0);
//    [gb+npart,+4): W1/W2 swizzle.
__global__ __launch_bounds__(256) void k_mega2(
    const float* __restrict__ x, const _Float16* __restrict__ Wsw0,
    _Float16* __restrict__ C, int M, int gb,
    const int* __restrict__ src, const int* __restrict__ dst,
    const int* __restrict__ bcnt, int* __restrict__ bCur,
    uint2* __restrict__ epart, int E, int npart,
    const float* __restrict__ W1, const float* __restrict__ W2,
    _Float16* __restrict__ Wsw12){
  __shared__ __align__(16) char smraw[5120 + PCH * 8];  // 21.5 KB union
  int bid = blockIdx.x;
  if (bid < gb){
    _Float16 (*lds)[136] = (_Float16(*)[136])(smraw + (threadIdx.x >> 6) * 16 * 136 * 2);
    int lane = threadIdx.x & 63;
    int quad = lane >> 4;
    int l15  = lane & 15;
    int m0 = bid * 64 + (threadIdx.x >> 6) * 16;
    if (m0 >= M) return;
    f4 acc[8] = {};
    h8 af[4];
    const float* arow = x + (size_t)(m0 + l15) * D;
    #pragma unroll
    for (int k0 = 0; k0 < 4; k0++){
      float4 a = *(const float4*)&arow[k0 * 32 + quad * 8];
      float4 b = *(const float4*)&arow[k0 * 32 + quad * 8 + 4];
      __half2 p0 = __floats2half2_rn(a.x, a.y);
      __half2 p1 = __floats2half2_rn(a.z, a.w);
      __half2 p2 = __floats2half2_rn(b.x, b.y);
      __half2 p3 = __floats2half2_rn(b.z, b.w);
      union { uint4 u; h8 v; } cv;
      cv.u.x = *(unsigned*)&p0; cv.u.y = *(unsigned*)&p1;
      cv.u.z = *(unsigned*)&p2; cv.u.w = *(unsigned*)&p3;
      af[k0] = cv.v;
    }
    #pragma unroll
    for (int k0 = 0; k0 < 4; k0++){
      #pragma unroll
      for (int t = 0; t < 8; t++){
        h8 bf = *(const h8*)&Wsw0[((size_t)(k0 * 8 + t) * 64 + lane) * 8];
        acc[t] = __builtin_amdgcn_mfma_f32_16x16x32_f16(af[k0], bf, acc[t], 0, 0, 0);
      }
    }
    #pragma unroll
    for (int t = 0; t < 8; t++){
      #pragma unroll
      for (int r = 0; r < 4; r++)
        lds[quad * 4 + r][t * 16 + l15] = (_Float16)acc[t][r];
    }
    #pragma unroll
    for (int it = 0; it < 4; it++){
      int idx = it * 64 + lane;
      int row = idx >> 4;
      int ch  = idx & 15;
      *(uint4*)&C[(size_t)(m0 + row) * D + ch * 8] = *(uint4*)&lds[row][ch * 8];
    }
    return;
  }
  bid -= gb;
  if (bid < npart){
    int* scnt  = (int*)smraw;
    int* soff  = (int*)(smraw + 1024);
    int* sbase = (int*)(smraw + 2048);
    int* scur  = (int*)(smraw + 3072);
    int* stmp  = (int*)(smraw + 4096);
    uint2* stage = (uint2*)(smraw + 5120);   // 16 KB
    int t = threadIdx.x;
    // --- global exclusive scan of bcnt (register) ---
    int bv = bcnt[t];
    stmp[t] = bv; __syncthreads();
    for (int off = 1; off < 256; off <<= 1){
      int xv = (t >= off) ? stmp[t - off] : 0;
      __syncthreads();
      stmp[t] += xv;
      __syncthreads();
    }
    int boffl = stmp[t] - bv;   // exclusive offset of bucket t
    __syncthreads();            // stmp reused below
    int e0 = bid * PCH;
    int eN = E - e0; if (eN > PCH) eN = PCH;
    for (int i = t; i < MAXBK; i += 256){ scnt[i] = 0; scur[i] = 0; }
    __syncthreads();
    uint2 mye[PCH / 256];
    #pragma unroll
    for (int j = 0; j < PCH / 256; j++){
      int e = e0 + t + j * 256;
      if (e < E){
        mye[j].x = (unsigned)src[e];
        mye[j].y = (unsigned)dst[e];
        atomicAdd(&scnt[mye[j].y >> BKSHIFT], 1);
      }
    }
    __syncthreads();
    int v = scnt[t];
    stmp[t] = v; __syncthreads();
    for (int off = 1; off < 256; off <<= 1){
      int xv = (t >= off) ? stmp[t - off] : 0;
      __syncthreads();
      stmp[t] += xv;
      __syncthreads();
    }
    soff[t] = stmp[t] - v;
    if (v > 0) sbase[t] = boffl + atomicAdd(&bCur[t], v);
    __syncthreads();
    #pragma unroll
    for (int j = 0; j < PCH / 256; j++){
      int e = e0 + t + j * 256;
      if (e < E){
        int b = mye[j].y >> BKSHIFT;
        int l = atomicAdd(&scur[b], 1);
        stage[soff[b] + l] = mye[j];
      }
    }
    __syncthreads();
    for (int j = t; j < eN; j += 256){
      uint2 ed = stage[j];
      int b = (int)(ed.y >> BKSHIFT);
      epart[(size_t)sbase[b] + (j - soff[b])] = ed;
    }
    return;
  }
  bid -= npart;
  const float* W = (bid < 2) ? W1 : W2;
  _Float16* dstp = Wsw12 + ((bid < 2) ? 0 : 16384);
  int pbase = (bid & 1) * 16;
  int lane = threadIdx.x & 63;
  for (int pp = (threadIdx.x >> 6); pp < 16; pp += 4)
    wcvt_pair(W, dstp, pbase + pp, lane);
}

// 2) per-bucket CSR build (512 threads): row_ptr, col, dinv
__global__ __launch_bounds__(512) void k_bfill(const uint2* __restrict__ epart,
    const int* __restrict__ bcnt, int* __restrict__ row_ptr,
    int* __restrict__ col, float* __restrict__ dinv, int N, int E){
  __shared__ int hc[BKNODES], cur[BKNODES];
  __shared__ int stmp[512];
  int b = blockIdx.x, t = threadIdx.x;
  // --- global exclusive scan of bcnt -> base of this bucket ---
  int bv = (t < MAXBK) ? bcnt[t] : 0;
  stmp[t] = bv; __syncthreads();
  for (int o = 1; o < 512; o <<= 1){
    int xv = (t >= o) ? stmp[t - o] : 0;
    __syncthreads();
    stmp[t] += xv;
    __syncthreads();
  }
  int cntE = bcnt[b];
  int base = stmp[b] - cntE;
  __syncthreads();  // stmp reused below
  if (b == (int)gridDim.x - 1 && t == 0) row_ptr[N] = E;
  int node0 = b << BKSHIFT;
  int nloc = N - node0; if (nloc > BKNODES) nloc = BKNODES;
  hc[t] = 0;
  __syncthreads();
  for (int j = t; j < cntE; j += 512){
    uint2 ed = epart[(size_t)base + j];
    atomicAdd(&hc[ed.y - node0], 1);
  }
  __syncthreads();
  int s = hc[t];
  stmp[t] = s; __syncthreads();
  for (int o = 1; o < 512; o <<= 1){
    int xv = (t >= o) ? stmp[t - o] : 0;
    __syncthreads();
    stmp[t] += xv;
    __syncthreads();
  }
  int ex = stmp[t] - s;
  if (t < nloc){
    row_ptr[node0 + t] = base + ex;
    dinv[node0 + t]    = rsqrtf((float)s + 1.0f);
  }
  cur[t] = ex;
  __syncthreads();
  for (int j = t; j < cntE; j += 512){
    uint2 ed = epart[(size_t)base + j];
    int p = atomicAdd(&cur[ed.y - node0], 1);
    col[base + p] = (int)ed.x;
  }
}

// accumulate 8 halves * w into acc[8]; (float)h * w + acc -> v_fma_mix_f32
__device__ __forceinline__ void accm(float* acc, uint4 u, float w){
  union { uint4 u; _Float16 h[8]; } cv;
  cv.u = u;
  #pragma unroll
  for (int k = 0; k < 8; k++)
    acc[k] += (float)cv.h[k] * w;
}

// 3) CSR aggregation: one wave per node, 4 gather chains/lane, fp16 in/out.
//    (layer 0 only: its GEMM already happened in k_mega2)
__global__ __launch_bounds__(256) void k_agg(const __half* __restrict__ t,
    const int* __restrict__ row_ptr, const int* __restrict__ col,
    const float* __restrict__ dinv, const float* __restrict__ bias,
    __half* __restrict__ outh, int relu, int N){
  int node = blockIdx.x * 4 + (threadIdx.x >> 6);
  if (node >= N) return;
  int lane = threadIdx.x & 63;
  int way  = lane >> 4;          // 0..3
  int cg   = (lane & 15) * 8;    // first col of this lane's 8-half group
  float di = dinv[node];
  int beg = row_ptr[node], end = row_ptr[node + 1];
  float acc[8] = {0.f,0.f,0.f,0.f,0.f,0.f,0.f,0.f};
  int j = beg + way;
  for (; j + 12 < end; j += 16){
    int s0 = col[j], s1 = col[j + 4], s2 = col[j + 8], s3 = col[j + 12];
    float w0 = dinv[s0] * di;
    float w1 = dinv[s1] * di;
    float w2 = dinv[s2] * di;
    float w3 = dinv[s3] * di;
    uint4 u0 = *(const uint4*)&t[(size_t)s0 * D + cg];
    uint4 u1 = *(const uint4*)&t[(size_t)s1 * D + cg];
    uint4 u2 = *(const uint4*)&t[(size_t)s2 * D + cg];
    uint4 u3 = *(const uint4*)&t[(size_t)s3 * D + cg];
    accm(acc, u0, w0);
    accm(acc, u1, w1);
    accm(acc, u2, w2);
    accm(acc, u3, w3);
  }
  for (; j < end; j += 4){
    int s = col[j];
    float w = dinv[s] * di;
    uint4 u = *(const uint4*)&t[(size_t)s * D + cg];
    accm(acc, u, w);
  }
  #pragma unroll
  for (int k = 0; k < 8; k++){
    acc[k] += __shfl_xor(acc[k], 16, 64);
    acc[k] += __shfl_xor(acc[k], 32, 64);
  }
  if (way == 0){
    uint4 su = *(const uint4*)&t[(size_t)node * D + cg];
    union { uint4 u; _Float16 h[8]; } sv; sv.u = su;
    float dii = di * di;
    float4 b0 = *(const float4*)&bias[cg];
    float4 b1 = *(const float4*)&bias[cg + 4];
    float bb[8] = {b0.x, b0.y, b0.z, b0.w, b1.x, b1.y, b1.z, b1.w};
    float o[8];
    #pragma unroll
    for (int k = 0; k < 8; k++)
      o[k] = acc[k] + (float)sv.h[k] * dii + bb[k];
    if (relu){
      #pragma unroll
      for (int k = 0; k < 8; k++) o[k] = fmaxf(o[k], 0.f);
    }
    __half2 p0 = __floats2half2_rn(o[0], o[1]);
    __half2 p1 = __floats2half2_rn(o[2], o[3]);
    __half2 p2 = __floats2half2_rn(o[4], o[5]);
    __half2 p3 = __floats2half2_rn(o[6], o[7]);
    uint4 u;
    u.x = *(unsigned*)&p0; u.y = *(unsigned*)&p1;
    u.z = *(unsigned*)&p2; u.w = *(unsigned*)&p3;
    *(uint4*)&outh[(size_t)node * D + cg] = u;
  }
}

// 4) FUSED layer, 16 waves / 1024 threads: ONE NODE PER WAVE (k_agg-granularity
//    latency hiding), one barrier, waves 0..7 do the 8 MFMA column tiles of
//    C = agg(h) @ W + b. Layer-1: store fp16 rows. Layer-2: segment-max pool
//    straight from LDS (h3 never hits HBM). __launch_bounds__(1024,8) keeps
//    VGPR<=64 -> 2 blocks/CU = 32 waves/CU.
__global__ __launch_bounds__(1024, 8) void k_aggw16(const __half* __restrict__ t,
    const int* __restrict__ row_ptr, const int* __restrict__ col,
    const float* __restrict__ dinv, const _Float16* __restrict__ Wsw,
    const float* __restrict__ bias, _Float16* __restrict__ outh,
    const int* __restrict__ batch, unsigned* __restrict__ pk,
    int relu, int dopool, int N){
  __shared__ _Float16 A[16][136];
  int wave = threadIdx.x >> 6;   // 0..15 = A-tile row = node
  int lane = threadIdx.x & 63;
  int way  = lane >> 4;          // gather chain id; also MFMA quad
  int l15  = lane & 15;
  int cg   = l15 * 8;
  int m0 = blockIdx.x * 16;
  int node = m0 + wave;
  // ---- phase 1: each wave aggregates its node into A[wave][:] ----
  if (node < N){
    float di = dinv[node];
    int beg = row_ptr[node], end = row_ptr[node + 1];
    float acc[8] = {0.f,0.f,0.f,0.f,0.f,0.f,0.f,0.f};
    int j = beg + way;
    for (; j + 12 < end; j += 16){
      int s0 = col[j], s1 = col[j + 4], s2 = col[j + 8], s3 = col[j + 12];
      float w0 = dinv[s0] * di;
      float w1 = dinv[s1] * di;
      float w2 = dinv[s2] * di;
      float w3 = dinv[s3] * di;
      uint4 u0 = *(const uint4*)&t[(size_t)s0 * D + cg];
      uint4 u1 = *(const uint4*)&t[(size_t)s1 * D + cg];
      uint4 u2 = *(const uint4*)&t[(size_t)s2 * D + cg];
      uint4 u3 = *(const uint4*)&t[(size_t)s3 * D + cg];
      accm(acc, u0, w0);
      accm(acc, u1, w1);
      accm(acc, u2, w2);
      accm(acc, u3, w3);
    }
    for (; j < end; j += 4){
      int s = col[j];
      float w = dinv[s] * di;
      uint4 u = *(const uint4*)&t[(size_t)s * D + cg];
      accm(acc, u, w);
    }
    #pragma unroll
    for (int k = 0; k < 8; k++){
      acc[k] += __shfl_xor(acc[k], 16, 64);
      acc[k] += __shfl_xor(acc[k], 32, 64);
    }
    if (way == 0){
      uint4 su = *(const uint4*)&t[(size_t)node * D + cg];
      union { uint4 u; _Float16 h[8]; } sv; sv.u = su;
      float dii = di * di;
      _Float16 o[8];
      #pragma unroll
      for (int k = 0; k < 8; k++)
        o[k] = (_Float16)(acc[k] + (float)sv.h[k] * dii);
      *(uint4*)&A[wave][cg] = *(uint4*)o;
    }
  } else if (way == 0){
    uint4 z = {0u, 0u, 0u, 0u};
    *(uint4*)&A[wave][cg] = z;
  }
  __syncthreads();
  // ---- phase 2: waves 0..7 each compute col-tile tt = wave ----
  h8 af[4];
  if (wave < 8){
    #pragma unroll
    for (int k0 = 0; k0 < 4; k0++)
      af[k0] = *(const h8*)&A[l15][k0 * 32 + way * 8];
  }
  __syncthreads();   // all af reads done; safe to overwrite A with C
  if (wave < 8){
    f4 c = {};
    #pragma unroll
    for (int k0 = 0; k0 < 4; k0++){
      h8 bfr = *(const h8*)&Wsw[((size_t)(k0 * 8 + wave) * 64 + lane) * 8];
      c = __builtin_amdgcn_mfma_f32_16x16x32_f16(af[k0], bfr, c, 0, 0, 0);
    }
    float b = bias[wave * 16 + l15];
    #pragma unroll
    for (int r = 0; r < 4; r++){
      float v = c[r] + b;
      if (relu) v = fmaxf(v, 0.f);
      A[way * 4 + r][wave * 16 + l15] = (_Float16)v;
    }
  }
  __syncthreads();
  if (!dopool){
    // coalesced store: threads 0..255 = 16 rows x 16 chunks of 8 halves
    if (threadIdx.x < 256){
      int row = threadIdx.x >> 4;
      int ch  = threadIdx.x & 15;
      if (m0 + row < N)
        *(uint4*)&outh[(size_t)(m0 + row) * D + ch * 8] = *(uint4*)&A[row][ch * 8];
    }
  } else {
    // fused segment-max pool from LDS (batch is sorted)
    if (threadIdx.x < 128){
      int d = threadIdx.x;
      int nEnd = N - m0; if (nEnd > 16) nEnd = 16;
      float cur = -FLT_MAX;
      int curg = batch[m0];
      for (int n = 0; n < nEnd; n++){
        int g = batch[m0 + n];
        if (g != curg){ atomicMax(&pk[curg * D + d], fkey(cur)); cur = -FLT_MAX; curg = g; }
        cur = fmaxf(cur, (float)A[n][d]);
      }
      atomicMax(&pk[curg * D + d], fkey(cur));
    }
  }
}

// 5) final: out[64,2] = pooled @ Wf + bf
__global__ __launch_bounds__(128) void k_final(const unsigned* __restrict__ pk,
    const float* __restrict__ Wf, const float* __restrict__ bf,
    float* __restrict__ out){
  int t = threadIdx.x;
  int g = t >> 1, c = t & 1;
  float s = bf[c];
  for (int k = 0; k < D; k++)
    s += funkey(pk[g * D + k]) * Wf[k * 2 + c];
  out[g * 2 + c] = s;
}

extern "C" void kernel_launch(void* const* d_in, const int* in_sizes, int n_in,
                              void* d_out, int out_size, void* d_ws, size_t ws_size,
                              hipStream_t stream){
  const float* x   = (const float*)d_in[0];
  const int*   ei  = (const int*)d_in[1];
  const int*   bat = (const int*)d_in[2];
  const float* W0  = (const float*)d_in[3];
  const float* b0  = (const float*)d_in[4];
  const float* W1  = (const float*)d_in[5];
  const float* b1  = (const float*)d_in[6];
  const float* W2  = (const float*)d_in[7];
  const float* b2  = (const float*)d_in[8];
  const float* Wf  = (const float*)d_in[9];
  const float* bf  = (const float*)d_in[10];
  int N = in_sizes[0] / D;
  int E = in_sizes[1] / 2;
  const int* srcp = ei;
  const int* dstp = ei + E;
  int nbk   = (N + BKNODES - 1) / BKNODES;
  int npart = (E + PCH - 1) / PCH;
  int nh    = (E + HCH - 1) / HCH;
  int gb    = (N + 63) / 64;

  char* p = (char*)d_ws;
  auto alloc = [&](size_t bytes)->char*{
    char* r = p; p += (bytes + 255) & ~(size_t)255; return r;
  };
  float*     dinv    = (float*)alloc((size_t)N * 4);
  int*       row_ptr = (int*)alloc((size_t)(N + 1) * 4);
  int*       col     = (int*)alloc((size_t)E * 4);
  uint2*     epart   = (uint2*)alloc((size_t)E * 8);
  _Float16*  tmp     = (_Float16*)alloc((size_t)N * D * 2);
  _Float16*  tmp2    = (_Float16*)alloc((size_t)N * D * 2);
  _Float16*  Wsw     = (_Float16*)alloc((size_t)3 * 16384 * 2);
  unsigned*  pk      = (unsigned*)alloc((size_t)NGRAPHS * D * 4);   // 32768 B
  int*       bcnt    = (int*)alloc((size_t)MAXBK * 4);              // 1024 B
  int*       bCur    = (int*)alloc((size_t)MAXBK * 4);              // 1024 B

  // zero pk + bcnt + bCur in one contiguous memset (allocs are adjacent)
  hipMemsetAsync(pk, 0, 32768 + 1024 + 1024, stream);
  // W0 swizzle + dst histogram
  k_wcvt0h<<<8 + nh, 256, 0, stream>>>(W0, Wsw, dstp, bcnt, E);
  // gemm0 (x -> tmp) || edge partition || W1/W2 swizzle
  k_mega2<<<gb + npart + 4, 256, 0, stream>>>(x, Wsw, tmp, N, gb,
      srcp, dstp, bcnt, bCur, epart, E, npart, W1, W2, Wsw + 16384);
  // per-bucket CSR build
  k_bfill<<<nbk, 512, 0, stream>>>(epart, bcnt, row_ptr, col, dinv, N, E);

  int ablocks = (N + 3) / 4;
  int fblocks = (N + 15) / 16;
  // layer 0: agg(tmp -> tmp2, +b0, relu)  (its GEMM was x@W0 in k_mega2)
  k_agg<<<ablocks, 256, 0, stream>>>((const __half*)tmp, row_ptr, col, dinv, b0, (__half*)tmp2, 1, N);
  // layer 1 fused: relu(agg(tmp2) @ W1 + b1) -> tmp
  k_aggw16<<<fblocks, 1024, 0, stream>>>((const __half*)tmp2, row_ptr, col, dinv,
      Wsw + 16384, b1, tmp, (const int*)nullptr, (unsigned*)nullptr, 1, 0, N);
  // layer 2 fused: (agg(tmp) @ W2 + b2) -> segment-max pool into pk
  k_aggw16<<<fblocks, 1024, 0, stream>>>((const __half*)tmp, row_ptr, col, dinv,
      Wsw + 32768, b2, (_Float16*)nullptr, bat, pk, 0, 1, N);
  // classifier
  k_final<<<1, 128, 0, stream>>>(pk, Wf, bf, (float*)d_out);
}

// Round 4
// 400.157 us; speedup vs baseline: 1.0532x; 1.0532x over previous
//
#include <hip/hip_runtime.h>
#include <hip/hip_bf16.h>
#include <hip/hip_fp16.h>
#include <float.h>

#define D 128
#define NGRAPHS 64
#define BKSHIFT 9
#define BKNODES 512     // nodes per bucket
#define MAXBK 256       // max buckets (N<=131072)
#define PCH 2048        // edges per partition block (256 thr x 8)
#define HCH 4096        // histogram chunk

typedef _Float16 h8 __attribute__((ext_vector_type(8)));
typedef float f4 __attribute__((ext_vector_type(4)));

// ---- ordered-float encoding for atomicMax on unsigned ----
__device__ __forceinline__ unsigned fkey(float f){
  unsigned u = __float_as_uint(f);
  return (u & 0x80000000u) ? ~u : (u | 0x80000000u);
}
__device__ __forceinline__ float funkey(unsigned k){
  unsigned u = (k & 0x80000000u) ? (k ^ 0x80000000u) : ~k;
  return __uint_as_float(u);
}

// ---- W fp32 row-major -> fp16 MFMA B-frag swizzle for one "pair" unit ----
__device__ __forceinline__ void wcvt_pair(const float* __restrict__ W,
    _Float16* __restrict__ dstp, int pair, int lane){
  int quad = lane >> 4;
  int n    = lane & 15;
  int k0 = pair >> 3;
  int tt = pair & 7;
  _Float16 v[8];
  #pragma unroll
  for (int j = 0; j < 8; j++){
    int k = k0 * 32 + quad * 8 + j;
    v[j] = (_Float16)W[k * 128 + 16 * tt + n];
  }
  *(uint4*)&dstp[((size_t)pair * 64 + lane) * 8] = *(uint4*)v;
}

// 0) W0 swizzle (blocks 0..7) + dst-bucket histogram (blocks 8..)
//    bcnt/bCur/pk zeroed by hipMemsetAsync before this kernel.
__global__ __launch_bounds__(256) void k_wcvt0h(const float* __restrict__ W0,
    _Float16* __restrict__ Wsw, const int* __restrict__ dst,
    int* __restrict__ bcnt, int E){
  __shared__ int h[MAXBK];
  if (blockIdx.x < 8){
    int lane = threadIdx.x & 63;
    int pair = blockIdx.x * 4 + (threadIdx.x >> 6);
    wcvt_pair(W0, Wsw, pair, lane);
    return;
  }
  int t = threadIdx.x;
  for (int i = t; i < MAXBK; i += 256) h[i] = 0;
  __syncthreads();
  int e0 = (blockIdx.x - 8) * HCH;
  #pragma unroll
  for (int j = 0; j < HCH / 256; j++){
    int e = e0 + t + j * 256;
    if (e < E) atomicAdd(&h[dst[e] >> BKSHIFT], 1);
  }
  __syncthreads();
  for (int i = t; i < MAXBK; i += 256) if (h[i]) atomicAdd(&bcnt[i], h[i]);
}

// 1) MEGA2: [0,gb): gemm0 fp32-A MFMA (x@W0 -> tmp, row-major);
//    [gb,gb+npart): edge partition into epart (hidden under gemm0);
//    [gb+npart,+4): W1/W2 swizzle.
__global__ __launch_bounds__(256) void k_mega2(
    const float* __restrict__ x, const _Float16* __restrict__ Wsw0,
    _Float16* __restrict__ C, int M, int gb,
    const int* __restrict__ src, const int* __restrict__ dst,
    const int* __restrict__ bcnt, int* __restrict__ bCur,
    uint2* __restrict__ epart, int E, int npart,
    const float* __restrict__ W1, const float* __restrict__ W2,
    _Float16* __restrict__ Wsw12){
  __shared__ __align__(16) char smraw[5120 + PCH * 8];  // 21.5 KB union
  int bid = blockIdx.x;
  if (bid < gb){
    _Float16 (*lds)[136] = (_Float16(*)[136])(smraw + (threadIdx.x >> 6) * 16 * 136 * 2);
    int lane = threadIdx.x & 63;
    int quad = lane >> 4;
    int l15  = lane & 15;
    int m0 = bid * 64 + (threadIdx.x >> 6) * 16;
    if (m0 >= M) return;
    f4 acc[8] = {};
    h8 af[4];
    const float* arow = x + (size_t)(m0 + l15) * D;
    #pragma unroll
    for (int k0 = 0; k0 < 4; k0++){
      float4 a = *(const float4*)&arow[k0 * 32 + quad * 8];
      float4 b = *(const float4*)&arow[k0 * 32 + quad * 8 + 4];
      __half2 p0 = __floats2half2_rn(a.x, a.y);
      __half2 p1 = __floats2half2_rn(a.z, a.w);
      __half2 p2 = __floats2half2_rn(b.x, b.y);
      __half2 p3 = __floats2half2_rn(b.z, b.w);
      union { uint4 u; h8 v; } cv;
      cv.u.x = *(unsigned*)&p0; cv.u.y = *(unsigned*)&p1;
      cv.u.z = *(unsigned*)&p2; cv.u.w = *(unsigned*)&p3;
      af[k0] = cv.v;
    }
    #pragma unroll
    for (int k0 = 0; k0 < 4; k0++){
      #pragma unroll
      for (int t = 0; t < 8; t++){
        h8 bf = *(const h8*)&Wsw0[((size_t)(k0 * 8 + t) * 64 + lane) * 8];
        acc[t] = __builtin_amdgcn_mfma_f32_16x16x32_f16(af[k0], bf, acc[t], 0, 0, 0);
      }
    }
    #pragma unroll
    for (int t = 0; t < 8; t++){
      #pragma unroll
      for (int r = 0; r < 4; r++)
        lds[quad * 4 + r][t * 16 + l15] = (_Float16)acc[t][r];
    }
    #pragma unroll
    for (int it = 0; it < 4; it++){
      int idx = it * 64 + lane;
      int row = idx >> 4;
      int ch  = idx & 15;
      *(uint4*)&C[(size_t)(m0 + row) * D + ch * 8] = *(uint4*)&lds[row][ch * 8];
    }
    return;
  }
  bid -= gb;
  if (bid < npart){
    int* scnt  = (int*)smraw;
    int* soff  = (int*)(smraw + 1024);
    int* sbase = (int*)(smraw + 2048);
    int* scur  = (int*)(smraw + 3072);
    int* stmp  = (int*)(smraw + 4096);
    uint2* stage = (uint2*)(smraw + 5120);   // 16 KB
    int t = threadIdx.x;
    // --- global exclusive scan of bcnt (register) ---
    int bv = bcnt[t];
    stmp[t] = bv; __syncthreads();
    for (int off = 1; off < 256; off <<= 1){
      int xv = (t >= off) ? stmp[t - off] : 0;
      __syncthreads();
      stmp[t] += xv;
      __syncthreads();
    }
    int boffl = stmp[t] - bv;   // exclusive offset of bucket t
    __syncthreads();            // stmp reused below
    int e0 = bid * PCH;
    int eN = E - e0; if (eN > PCH) eN = PCH;
    for (int i = t; i < MAXBK; i += 256){ scnt[i] = 0; scur[i] = 0; }
    __syncthreads();
    uint2 mye[PCH / 256];
    #pragma unroll
    for (int j = 0; j < PCH / 256; j++){
      int e = e0 + t + j * 256;
      if (e < E){
        mye[j].x = (unsigned)src[e];
        mye[j].y = (unsigned)dst[e];
        atomicAdd(&scnt[mye[j].y >> BKSHIFT], 1);
      }
    }
    __syncthreads();
    int v = scnt[t];
    stmp[t] = v; __syncthreads();
    for (int off = 1; off < 256; off <<= 1){
      int xv = (t >= off) ? stmp[t - off] : 0;
      __syncthreads();
      stmp[t] += xv;
      __syncthreads();
    }
    soff[t] = stmp[t] - v;
    if (v > 0) sbase[t] = boffl + atomicAdd(&bCur[t], v);
    __syncthreads();
    #pragma unroll
    for (int j = 0; j < PCH / 256; j++){
      int e = e0 + t + j * 256;
      if (e < E){
        int b = mye[j].y >> BKSHIFT;
        int l = atomicAdd(&scur[b], 1);
        stage[soff[b] + l] = mye[j];
      }
    }
    __syncthreads();
    for (int j = t; j < eN; j += 256){
      uint2 ed = stage[j];
      int b = (int)(ed.y >> BKSHIFT);
      epart[(size_t)sbase[b] + (j - soff[b])] = ed;
    }
    return;
  }
  bid -= npart;
  const float* W = (bid < 2) ? W1 : W2;
  _Float16* dstp = Wsw12 + ((bid < 2) ? 0 : 16384);
  int pbase = (bid & 1) * 16;
  int lane = threadIdx.x & 63;
  for (int pp = (threadIdx.x >> 6); pp < 16; pp += 4)
    wcvt_pair(W, dstp, pbase + pp, lane);
}

// 2) per-bucket CSR build (512 threads): row_ptr, col, dinv
__global__ __launch_bounds__(512) void k_bfill(const uint2* __restrict__ epart,
    const int* __restrict__ bcnt, int* __restrict__ row_ptr,
    int* __restrict__ col, float* __restrict__ dinv, int N, int E){
  __shared__ int hc[BKNODES], cur[BKNODES];
  __shared__ int stmp[512];
  int b = blockIdx.x, t = threadIdx.x;
  // --- global exclusive scan of bcnt -> base of this bucket ---
  int bv = (t < MAXBK) ? bcnt[t] : 0;
  stmp[t] = bv; __syncthreads();
  for (int o = 1; o < 512; o <<= 1){
    int xv = (t >= o) ? stmp[t - o] : 0;
    __syncthreads();
    stmp[t] += xv;
    __syncthreads();
  }
  int cntE = bcnt[b];
  int base = stmp[b] - cntE;
  __syncthreads();  // stmp reused below
  if (b == (int)gridDim.x - 1 && t == 0) row_ptr[N] = E;
  int node0 = b << BKSHIFT;
  int nloc = N - node0; if (nloc > BKNODES) nloc = BKNODES;
  hc[t] = 0;
  __syncthreads();
  for (int j = t; j < cntE; j += 512){
    uint2 ed = epart[(size_t)base + j];
    atomicAdd(&hc[ed.y - node0], 1);
  }
  __syncthreads();
  int s = hc[t];
  stmp[t] = s; __syncthreads();
  for (int o = 1; o < 512; o <<= 1){
    int xv = (t >= o) ? stmp[t - o] : 0;
    __syncthreads();
    stmp[t] += xv;
    __syncthreads();
  }
  int ex = stmp[t] - s;
  if (t < nloc){
    row_ptr[node0 + t] = base + ex;
    dinv[node0 + t]    = rsqrtf((float)s + 1.0f);
  }
  cur[t] = ex;
  __syncthreads();
  for (int j = t; j < cntE; j += 512){
    uint2 ed = epart[(size_t)base + j];
    int p = atomicAdd(&cur[ed.y - node0], 1);
    col[base + p] = (int)ed.x;
  }
}

// accumulate 8 halves * w into acc[8]; (float)h * w + acc -> v_fma_mix_f32
__device__ __forceinline__ void accm(float* acc, uint4 u, float w){
  union { uint4 u; _Float16 h[8]; } cv;
  cv.u = u;
  #pragma unroll
  for (int k = 0; k < 8; k++)
    acc[k] += (float)cv.h[k] * w;
}

// 3) CSR aggregation: one wave per node, 4 gather chains/lane, fp16 in/out.
//    Independent 4-wave blocks: no barrier, blocks retire as soon as their
//    own nodes finish (measured best: 66 us, 3.4 TB/s, occ 70%).
__global__ __launch_bounds__(256) void k_agg(const __half* __restrict__ t,
    const int* __restrict__ row_ptr, const int* __restrict__ col,
    const float* __restrict__ dinv, const float* __restrict__ bias,
    __half* __restrict__ outh, int relu, int N){
  int node = blockIdx.x * 4 + (threadIdx.x >> 6);
  if (node >= N) return;
  int lane = threadIdx.x & 63;
  int way  = lane >> 4;          // 0..3
  int cg   = (lane & 15) * 8;    // first col of this lane's 8-half group
  float di = dinv[node];
  int beg = row_ptr[node], end = row_ptr[node + 1];
  float acc[8] = {0.f,0.f,0.f,0.f,0.f,0.f,0.f,0.f};
  int j = beg + way;
  for (; j + 12 < end; j += 16){
    int s0 = col[j], s1 = col[j + 4], s2 = col[j + 8], s3 = col[j + 12];
    float w0 = dinv[s0] * di;
    float w1 = dinv[s1] * di;
    float w2 = dinv[s2] * di;
    float w3 = dinv[s3] * di;
    uint4 u0 = *(const uint4*)&t[(size_t)s0 * D + cg];
    uint4 u1 = *(const uint4*)&t[(size_t)s1 * D + cg];
    uint4 u2 = *(const uint4*)&t[(size_t)s2 * D + cg];
    uint4 u3 = *(const uint4*)&t[(size_t)s3 * D + cg];
    accm(acc, u0, w0);
    accm(acc, u1, w1);
    accm(acc, u2, w2);
    accm(acc, u3, w3);
  }
  for (; j < end; j += 4){
    int s = col[j];
    float w = dinv[s] * di;
    uint4 u = *(const uint4*)&t[(size_t)s * D + cg];
    accm(acc, u, w);
  }
  #pragma unroll
  for (int k = 0; k < 8; k++){
    acc[k] += __shfl_xor(acc[k], 16, 64);
    acc[k] += __shfl_xor(acc[k], 32, 64);
  }
  if (way == 0){
    uint4 su = *(const uint4*)&t[(size_t)node * D + cg];
    union { uint4 u; _Float16 h[8]; } sv; sv.u = su;
    float dii = di * di;
    float4 b0 = *(const float4*)&bias[cg];
    float4 b1 = *(const float4*)&bias[cg + 4];
    float bb[8] = {b0.x, b0.y, b0.z, b0.w, b1.x, b1.y, b1.z, b1.w};
    float o[8];
    #pragma unroll
    for (int k = 0; k < 8; k++)
      o[k] = acc[k] + (float)sv.h[k] * dii + bb[k];
    if (relu){
      #pragma unroll
      for (int k = 0; k < 8; k++) o[k] = fmaxf(o[k], 0.f);
    }
    __half2 p0 = __floats2half2_rn(o[0], o[1]);
    __half2 p1 = __floats2half2_rn(o[2], o[3]);
    __half2 p2 = __floats2half2_rn(o[4], o[5]);
    __half2 p3 = __floats2half2_rn(o[6], o[7]);
    uint4 u;
    u.x = *(unsigned*)&p0; u.y = *(unsigned*)&p1;
    u.z = *(unsigned*)&p2; u.w = *(unsigned*)&p3;
    *(uint4*)&outh[(size_t)node * D + cg] = u;
  }
}

// 4) MFMA GEMM, fp16 A (row-major) -> fp16 C (row-major)
__global__ __launch_bounds__(256) void gemm_mfma(const _Float16* __restrict__ A,
    const _Float16* __restrict__ Wsw, _Float16* __restrict__ C, int M){
  __shared__ _Float16 lds[4][16][136];
  int wave = threadIdx.x >> 6;
  int lane = threadIdx.x & 63;
  int quad = lane >> 4;
  int l15  = lane & 15;
  int m0 = blockIdx.x * 64 + wave * 16;
  if (m0 >= M) return;
  f4 acc[8] = {};
  h8 af[4];
  const _Float16* arow = A + (size_t)(m0 + l15) * D;
  #pragma unroll
  for (int k0 = 0; k0 < 4; k0++)
    af[k0] = *(const h8*)&arow[k0 * 32 + quad * 8];
  #pragma unroll
  for (int k0 = 0; k0 < 4; k0++){
    #pragma unroll
    for (int t = 0; t < 8; t++){
      h8 bf = *(const h8*)&Wsw[((size_t)(k0 * 8 + t) * 64 + lane) * 8];
      acc[t] = __builtin_amdgcn_mfma_f32_16x16x32_f16(af[k0], bf, acc[t], 0, 0, 0);
    }
  }
  #pragma unroll
  for (int t = 0; t < 8; t++){
    #pragma unroll
    for (int r = 0; r < 4; r++)
      lds[wave][quad * 4 + r][t * 16 + l15] = (_Float16)acc[t][r];
  }
  #pragma unroll
  for (int it = 0; it < 4; it++){
    int idx = it * 64 + lane;
    int row = idx >> 4;
    int ch  = idx & 15;
    *(uint4*)&C[(size_t)(m0 + row) * D + ch * 8] = *(uint4*)&lds[wave][row][ch * 8];
  }
}

// 5) chunked segment-max (fp16 input), 64-row chunks, 4-deep load batching.
__global__ __launch_bounds__(128) void k_pool(const __half* __restrict__ h,
    const int* __restrict__ batch, unsigned* __restrict__ pk, int N){
  int d = threadIdx.x;
  int n0 = blockIdx.x * 64;
  int nEnd = n0 + 64; if (nEnd > N) nEnd = N;
  float cur = -FLT_MAX;
  int curg = batch[n0];
  int n = n0;
  for (; n + 3 < nEnd; n += 4){
    const __half* r = &h[(size_t)n * D + d];
    __half v0 = r[0], v1 = r[D], v2 = r[2 * D], v3 = r[3 * D];
    int g0 = batch[n], g1 = batch[n + 1], g2 = batch[n + 2], g3 = batch[n + 3];
    if (g0 != curg){ atomicMax(&pk[curg * D + d], fkey(cur)); cur = -FLT_MAX; curg = g0; }
    cur = fmaxf(cur, __half2float(v0));
    if (g1 != curg){ atomicMax(&pk[curg * D + d], fkey(cur)); cur = -FLT_MAX; curg = g1; }
    cur = fmaxf(cur, __half2float(v1));
    if (g2 != curg){ atomicMax(&pk[curg * D + d], fkey(cur)); cur = -FLT_MAX; curg = g2; }
    cur = fmaxf(cur, __half2float(v2));
    if (g3 != curg){ atomicMax(&pk[curg * D + d], fkey(cur)); cur = -FLT_MAX; curg = g3; }
    cur = fmaxf(cur, __half2float(v3));
  }
  for (; n < nEnd; n++){
    int g = batch[n];
    if (g != curg){ atomicMax(&pk[curg * D + d], fkey(cur)); cur = -FLT_MAX; curg = g; }
    cur = fmaxf(cur, __half2float(h[(size_t)n * D + d]));
  }
  atomicMax(&pk[curg * D + d], fkey(cur));
}

// 6) final: out[64,2] = pooled @ Wf + bf
__global__ __launch_bounds__(128) void k_final(const unsigned* __restrict__ pk,
    const float* __restrict__ Wf, const float* __restrict__ bf,
    float* __restrict__ out){
  int t = threadIdx.x;
  int g = t >> 1, c = t & 1;
  float s = bf[c];
  for (int k = 0; k < D; k++)
    s += funkey(pk[g * D + k]) * Wf[k * 2 + c];
  out[g * 2 + c] = s;
}

extern "C" void kernel_launch(void* const* d_in, const int* in_sizes, int n_in,
                              void* d_out, int out_size, void* d_ws, size_t ws_size,
                              hipStream_t stream){
  const float* x   = (const float*)d_in[0];
  const int*   ei  = (const int*)d_in[1];
  const int*   bat = (const int*)d_in[2];
  const float* W0  = (const float*)d_in[3];
  const float* b0  = (const float*)d_in[4];
  const float* W1  = (const float*)d_in[5];
  const float* b1  = (const float*)d_in[6];
  const float* W2  = (const float*)d_in[7];
  const float* b2  = (const float*)d_in[8];
  const float* Wf  = (const float*)d_in[9];
  const float* bf  = (const float*)d_in[10];
  int N = in_sizes[0] / D;
  int E = in_sizes[1] / 2;
  const int* srcp = ei;
  const int* dstp = ei + E;
  int nbk   = (N + BKNODES - 1) / BKNODES;
  int npart = (E + PCH - 1) / PCH;
  int nh    = (E + HCH - 1) / HCH;
  int gb    = (N + 63) / 64;

  char* p = (char*)d_ws;
  auto alloc = [&](size_t bytes)->char*{
    char* r = p; p += (bytes + 255) & ~(size_t)255; return r;
  };
  float*     dinv    = (float*)alloc((size_t)N * 4);
  int*       row_ptr = (int*)alloc((size_t)(N + 1) * 4);
  int*       col     = (int*)alloc((size_t)E * 4);
  uint2*     epart   = (uint2*)alloc((size_t)E * 8);
  _Float16*  tmp     = (_Float16*)alloc((size_t)N * D * 2);
  _Float16*  tmp2    = (_Float16*)alloc((size_t)N * D * 2);
  _Float16*  Wsw     = (_Float16*)alloc((size_t)3 * 16384 * 2);
  unsigned*  pk      = (unsigned*)alloc((size_t)NGRAPHS * D * 4);   // 32768 B
  int*       bcnt    = (int*)alloc((size_t)MAXBK * 4);              // 1024 B
  int*       bCur    = (int*)alloc((size_t)MAXBK * 4);              // 1024 B

  // zero pk + bcnt + bCur in one contiguous memset (allocs are adjacent)
  hipMemsetAsync(pk, 0, 32768 + 1024 + 1024, stream);
  // W0 swizzle + dst histogram
  k_wcvt0h<<<8 + nh, 256, 0, stream>>>(W0, Wsw, dstp, bcnt, E);
  // gemm0 (x -> tmp) || edge partition || W1/W2 swizzle
  k_mega2<<<gb + npart + 4, 256, 0, stream>>>(x, Wsw, tmp, N, gb,
      srcp, dstp, bcnt, bCur, epart, E, npart, W1, W2, Wsw + 16384);
  // per-bucket CSR build
  k_bfill<<<nbk, 512, 0, stream>>>(epart, bcnt, row_ptr, col, dinv, N, E);

  int ablocks = (N + 3) / 4;
  // layer 0: agg(tmp -> tmp2, +b0, relu)  (its GEMM was x@W0 in k_mega2)
  k_agg<<<ablocks, 256, 0, stream>>>((const __half*)tmp, row_ptr, col, dinv, b0, (__half*)tmp2, 1, N);
  // layer 1: gemm(tmp2 -> tmp), agg(tmp -> tmp2, relu)
  gemm_mfma<<<gb, 256, 0, stream>>>(tmp2, Wsw + 16384, tmp, N);
  k_agg<<<ablocks, 256, 0, stream>>>((const __half*)tmp, row_ptr, col, dinv, b1, (__half*)tmp2, 1, N);
  // layer 2: gemm(tmp2 -> tmp), agg(tmp -> tmp2, no relu)
  gemm_mfma<<<gb, 256, 0, stream>>>(tmp2, Wsw + 32768, tmp, N);
  k_agg<<<ablocks, 256, 0, stream>>>((const __half*)tmp, row_ptr, col, dinv, b2, (__half*)tmp2, 0, N);
  // pool + classifier
  k_pool<<<(N + 63) / 64, 128, 0, stream>>>((const __half*)tmp2, bat, pk, N);
  k_final<<<1, 128, 0, stream>>>(pk, Wf, bf, (float*)d_out);
}